// Round 1
// baseline (726.877 us; speedup 1.0000x reference)
//
#include <hip/hip_runtime.h>
#include <stdint.h>

#define PRIME 2147483647LL
#define NUM_EMB 100000
#define NUM_BUCKETS 65536
#define EMB 64
#define N_ARY 32
#define NDIG 16

struct HashConsts {
  long long seqA[NDIG];
  long long hashA[2];
  long long hashB[2];
};

// One block per b (4096 blocks). 4 waves/block; wave w handles d = 4w..4w+3.
// Each wave: 4 items x 2 rows x 8KB = 64KB of loads -> 4x deeper MLP than 1-item waves.
// All wave-uniform quantities (bucket bases, importance weights) are forced to SGPRs.
__global__ __launch_bounds__(256, 4) void hash_logits_kernel(
    const int* __restrict__ seq,    // [B,16] int32
    const float* __restrict__ rep,  // [B,16,64]
    const float* __restrict__ iw,   // [NUM_EMB,2]
    const float* __restrict__ bt,   // [NUM_BUCKETS, 2048]
    float* __restrict__ out,        // [B,16,32]
    HashConsts hc)
{
  const int b    = blockIdx.x;
  const int wave = threadIdx.x >> 6;
  const int lane = threadIdx.x & 63;
  const int g    = lane >> 4;   // 0..3 (output a-group)
  const int sub  = lane & 15;   // 0..15 (e-fragment)

  // ---- hoist rep loads: independent of the hash chain, overlap its latency ----
  float4 r[4];
#pragma unroll
  for (int i = 0; i < 4; ++i) {
    const int d = 4 * wave + i;
    r[i] = *(const float4*)(rep + ((size_t)b * NDIG + d) * EMB + sub * 4);
  }

  // ---- prefix-hash ids for the wave's 4 d's (uniform across the wave) ----
  const int* srow = seq + b * NDIG;
  int v[NDIG];
  int len = 0;
#pragma unroll
  for (int j = 0; j < NDIG; ++j) { v[j] = srow[j]; len += (v[j] != 0); }
  const int lm1 = max(len - 1, 0);

  int idxv[4];
#pragma unroll
  for (int i = 0; i < 4; ++i) idxv[i] = min(4 * wave + i, lm1);

  long long cap[4];
  long long acc = 0;
#pragma unroll
  for (int j = 0; j < NDIG; ++j) {
    acc += hc.seqA[j] * (long long)v[j];  // < 2^40 total (v < 32)
#pragma unroll
    for (int i = 0; i < 4; ++i)
      if (j == idxv[i]) cap[i] = acc;
  }

  const float4* base0[4];
  const float4* base1[4];
  float w0f[4], w1f[4];
#pragma unroll
  for (int i = 0; i < 4; ++i) {
    // exact mod 2^31-1 via Mersenne folds (acc < 2^40)
    unsigned long long x = (unsigned long long)cap[i];
    x = (x & (unsigned long long)PRIME) + (x >> 31);   // < 2^31 + 2^9
    x = (x & (unsigned long long)PRIME) + (x >> 31);   // <= PRIME
    unsigned int id = (unsigned int)x;
    if (id >= (unsigned int)PRIME) id -= (unsigned int)PRIME;
    id = (unsigned int)__builtin_amdgcn_readfirstlane((int)id);  // -> SGPR

    const unsigned int widx = id % 100000u;  // const divisor -> magic mul
    const float2 wv = *(const float2*)(iw + (size_t)widx * 2);
    w0f[i] = __int_as_float(__builtin_amdgcn_readfirstlane(__float_as_int(wv.x)));
    w1f[i] = __int_as_float(__builtin_amdgcn_readfirstlane(__float_as_int(wv.y)));

#pragma unroll
    for (int h = 0; h < 2; ++h) {
      unsigned long long t =
          (unsigned long long)hc.hashA[h] * id + (unsigned long long)hc.hashB[h];  // < 2^62+2^31
      t = (t & (unsigned long long)PRIME) + (t >> 31);  // < 2^32
      t = (t & (unsigned long long)PRIME) + (t >> 31);  // <= PRIME+1
      unsigned int z = (unsigned int)t;
      if (z >= (unsigned int)PRIME) z -= (unsigned int)PRIME;
      const int bk = __builtin_amdgcn_readfirstlane((int)(z & (NUM_BUCKETS - 1)));
      const float4* base = (const float4*)bt + ((size_t)(unsigned)bk << 9);  // 512 float4/row
      if (h == 0) base0[i] = base; else base1[i] = base;
    }
  }

  // ---- main loop: 8 k-steps x 4 items, 8 coalesced 1KB loads in flight per step ----
  float s[4][8];
#pragma unroll
  for (int k = 0; k < 8; ++k) {
    float4 a0[4], a1[4];
#pragma unroll
    for (int i = 0; i < 4; ++i) {
      a0[i] = base0[i][lane + 64 * k];
      a1[i] = base1[i][lane + 64 * k];
    }
#pragma unroll
    for (int i = 0; i < 4; ++i) {
      const float d0 = a0[i].x * r[i].x + a0[i].y * r[i].y + a0[i].z * r[i].z + a0[i].w * r[i].w;
      const float d1 = a1[i].x * r[i].x + a1[i].y * r[i].y + a1[i].z * r[i].z + a1[i].w * r[i].w;
      s[i][k] = w0f[i] * d0 + w1f[i] * d1;
    }
  }

  // ---- reduce over the 16-lane subgroup (sub bits); g bits untouched ----
#pragma unroll
  for (int m = 1; m <= 8; m <<= 1)
#pragma unroll
    for (int i = 0; i < 4; ++i)
#pragma unroll
      for (int k = 0; k < 8; ++k)
        s[i][k] += __shfl_xor(s[i][k], m, 64);

  if (sub == 0) {
#pragma unroll
    for (int i = 0; i < 4; ++i) {
      float* obase = out + ((size_t)b * NDIG + (4 * wave + i)) * N_ARY + g;
#pragma unroll
      for (int k = 0; k < 8; ++k) obase[4 * k] = s[i][k];  // a = g + 4k
    }
  }
}

extern "C" void kernel_launch(void* const* d_in, const int* in_sizes, int n_in,
                              void* d_out, int out_size, void* d_ws, size_t ws_size,
                              hipStream_t stream) {
  // ---- reproduce np.random.RandomState(42) module-level constants on host ----
  uint32_t mt[624];
  int mti;
  mt[0] = 42u;
  for (int i = 1; i < 624; ++i)
    mt[i] = 1812433253u * (mt[i - 1] ^ (mt[i - 1] >> 30)) + (uint32_t)i;
  mti = 624;
  auto next32 = [&]() -> uint32_t {
    if (mti >= 624) {
      for (int i = 0; i < 624; ++i) {
        uint32_t y = (mt[i] & 0x80000000u) | (mt[(i + 1) % 624] & 0x7fffffffu);
        uint32_t x = mt[(i + 397) % 624] ^ (y >> 1);
        if (y & 1u) x ^= 2567483615u;
        mt[i] = x;
      }
      mti = 0;
    }
    uint32_t y = mt[mti++];
    y ^= y >> 11;
    y ^= (y << 7) & 2636928640u;
    y ^= (y << 15) & 4022730752u;
    y ^= y >> 18;
    return y;
  };
  auto draw = [&](uint32_t rng_incl) -> uint32_t {
    uint32_t val;
    do { val = next32() & 0x7FFFFFFFu; } while (val > rng_incl);
    return val;
  };
  HashConsts hc;
  for (int i = 0; i < NDIG; ++i) hc.seqA[i] = 1LL + (long long)draw(2147483645u);
  for (int i = 0; i < 2; ++i)    hc.hashA[i] = 1LL + (long long)draw(2147483645u);
  for (int i = 0; i < 2; ++i)    hc.hashB[i] = (long long)draw(2147483646u);

  const int*   seq = (const int*)d_in[0];
  const float* rep = (const float*)d_in[1];
  const float* iw  = (const float*)d_in[2];
  const float* bt  = (const float*)d_in[3];
  float*       out = (float*)d_out;

  const int B = in_sizes[0] / NDIG;  // 4096
  dim3 grid(B), block(256);
  hipLaunchKernelGGL(hash_logits_kernel, grid, block, 0, stream,
                     seq, rep, iw, bt, out, hc);
}